// Round 15
// baseline (464.993 us; speedup 1.0000x reference)
//
#include <hip/hip_runtime.h>
#include <hip/hip_bf16.h>

// Problem constants
static constexpr int B   = 64;
static constexpr int CIN = 2048;
static constexpr int O   = 256;    // out channels = d
static constexpr int HW  = 196;    // 14*14 = M
static constexpr int D   = 256;    // matrix dim
static constexpr int TRI = 32896;  // D*(D+1)/2
static constexpr int NQ_COUPLED = 5; // coupled iters AFTER the identity iter0
static constexpr size_t NELEM = (size_t)B * D * D;   // 4,194,304
static constexpr size_t YN    = (size_t)B * O * HW;  // 3,211,264

typedef unsigned short u16;
typedef unsigned short u16x4 __attribute__((ext_vector_type(4)));
typedef unsigned short u16x8 __attribute__((ext_vector_type(8)));
typedef __bf16         bf16x8 __attribute__((ext_vector_type(8)));
typedef float          f32x4 __attribute__((ext_vector_type(4)));

static __device__ __forceinline__ u16 f2bf(float x) {
    unsigned int u = __float_as_uint(x);
    u += 0x7FFFu + ((u >> 16) & 1u);          // round-to-nearest-even
    return (u16)(u >> 16);
}
static __device__ __forceinline__ float bf2f(u16 h) {
    return __uint_as_float(((unsigned int)h) << 16);
}
static __device__ __forceinline__ f32x4 mm_bf16(u16x8 a, u16x8 b, f32x4 c) {
    return __builtin_amdgcn_mfma_f32_16x16x32_bf16(
        __builtin_bit_cast(bf16x8, a), __builtin_bit_cast(bf16x8, b), c, 0, 0, 0);
}

// ---------------------------------------------------------------------------
// K0: split W fp32 -> bf16 (Wh, Wl) planes, once
// ---------------------------------------------------------------------------
__global__ __launch_bounds__(256) void k_wsplit(const float* __restrict__ W,
                                                u16* __restrict__ Wh,
                                                u16* __restrict__ Wl) {
    const size_t i = (size_t)blockIdx.x * 256 + threadIdx.x;
    const float v = W[i];
    const u16 h = f2bf(v);
    Wh[i] = h;
    Wl[i] = f2bf(v - bf2f(h));
}

// ---------------------------------------------------------------------------
// K1: conv = W(256x2048) * X(2048x12544), bf16 2-plane split MFMA.
//     128x128 tile per block, 4 waves, each wave a 64x64 register tile.
//     K-split 4 (784 blocks), K-step 32, LDS stride 40 (80 B rows, 16-B
//     aligned).  convX uses native __bf16 casts (round-14 verified:
//     VALUBusy 16->10%).
// ---------------------------------------------------------------------------
__global__ __launch_bounds__(256, 3) void k_conv(const float* __restrict__ x,
                                                 const u16* __restrict__ Wh,
                                                 const u16* __restrict__ Wl,
                                                 float* __restrict__ psum) {
    const int l   = blockIdx.x;
    const int xcd = l & 7, u = l >> 3;        // u 0..97
    const int q   = xcd * 98 + u;             // 0..783, XCD-affine
    const int ks  = q & 3;
    const int t2  = q >> 2;                   // 0..195
    const int ot  = t2 & 1, gt = t2 >> 1;     // gt 0..97
    const int o0  = ot * 128;
    const int cbase = ks * 512;
    float* yp = psum + (size_t)ks * YN;

    const int tid = threadIdx.x;

    __shared__ u16 sW[2][128][40], sX[2][128][40];   // [plane][row][k], 40 KB

    // per-thread X staging column (constant per thread)
    const int colX  = tid & 127;
    const int chalf = (tid >> 7) * 16;        // c-offset 0 or 16
    const int gX = gt * 128 + colX;
    const int bX = gX / 196;
    const int mX = gX - bX * 196;
    const size_t xbase = (size_t)bX * (CIN * HW) + mX;   // + c*HW

    // W staging: thread -> row, k-half (16 elems)
    const int rW = tid >> 1, kq = (tid & 1) * 16;
    const u16* gWh = Wh + (size_t)(o0 + rW) * CIN + cbase + kq;
    const u16* gWl = Wl + (size_t)(o0 + rW) * CIN + cbase + kq;

    const int lane = tid & 63, w = tid >> 6;
    const int wr = w >> 1, wc = w & 1;
    const int lr = lane & 15, lg = lane >> 4, ko = lg << 3;

    f32x4 acc[4][4] = {};

    u16x8 pWh[2], pWl[2];
    float pX[16];
    u16x4 cXh[4], cXl[4];

    auto loadW = [&](int kb) {
        #pragma unroll
        for (int qq = 0; qq < 2; ++qq) {
            pWh[qq] = *(const u16x8*)&gWh[kb + qq * 8];
            pWl[qq] = *(const u16x8*)&gWl[kb + qq * 8];
        }
    };
    auto loadX = [&](int kb) {
        #pragma unroll
        for (int i = 0; i < 16; ++i)
            pX[i] = x[xbase + (size_t)(cbase + kb + chalf + i) * HW];
    };
    auto convX = [&]() {
        #pragma unroll
        for (int i = 0; i < 16; i += 4) {
            u16x4 vh, vl;
            #pragma unroll
            for (int j = 0; j < 4; ++j) {
                const float v = pX[i + j];
                const __bf16 hb = (__bf16)v;          // RNE == f2bf
                const float  hf = (float)hb;          // exact (shift)
                const __bf16 lb = (__bf16)(v - hf);   // RNE == f2bf
                vh[j] = __builtin_bit_cast(u16, hb);
                vl[j] = __builtin_bit_cast(u16, lb);
            }
            cXh[i >> 2] = vh;
            cXl[i >> 2] = vl;
        }
    };
    auto storeWX = [&]() {
        #pragma unroll
        for (int qq = 0; qq < 2; ++qq) {
            *(u16x8*)&sW[0][rW][kq + qq * 8] = pWh[qq];
            *(u16x8*)&sW[1][rW][kq + qq * 8] = pWl[qq];
        }
        #pragma unroll
        for (int qq = 0; qq < 4; ++qq) {
            *(u16x4*)&sX[0][colX][chalf + qq * 4] = cXh[qq];
            *(u16x4*)&sX[1][colX][chalf + qq * 4] = cXl[qq];
        }
    };
    auto compute = [&]() {
        u16x8 fah[4], fal[4], fbh[4], fbl[4];
        #pragma unroll
        for (int f = 0; f < 4; ++f) {
            fah[f] = *(const u16x8*)&sW[0][wr * 64 + f * 16 + lr][ko];
            fal[f] = *(const u16x8*)&sW[1][wr * 64 + f * 16 + lr][ko];
            fbh[f] = *(const u16x8*)&sX[0][wc * 64 + f * 16 + lr][ko];
            fbl[f] = *(const u16x8*)&sX[1][wc * 64 + f * 16 + lr][ko];
        }
        #pragma unroll
        for (int fi = 0; fi < 4; ++fi)
            #pragma unroll
            for (int fj = 0; fj < 4; ++fj) {
                acc[fi][fj] = mm_bf16(fah[fi], fbh[fj], acc[fi][fj]);
                acc[fi][fj] = mm_bf16(fah[fi], fbl[fj], acc[fi][fj]);
                acc[fi][fj] = mm_bf16(fal[fi], fbh[fj], acc[fi][fj]);
            }
    };

    loadW(0); loadX(0); convX();
    for (int st = 0; st < 16; ++st) {
        __syncthreads();                  // all reads of previous K-step done
        storeWX();
        __syncthreads();                  // buffer ready
        if (st < 15) { loadW((st + 1) * 32); loadX((st + 1) * 32); }
        compute();
        if (st < 15) convX();
    }

    // epilogue: psum[ks][b][o][m]
    #pragma unroll
    for (int fj = 0; fj < 4; ++fj) {
        const int gcol = gt * 128 + wc * 64 + fj * 16 + lr;
        const int bb = gcol / 196;
        const int mm = gcol - bb * 196;
        const size_t ybase = (size_t)bb * (O * HW) + mm;
        #pragma unroll
        for (int fi = 0; fi < 4; ++fi)
            #pragma unroll
            for (int r = 0; r < 4; ++r) {
                const int orow = o0 + wr * 64 + fi * 16 + (lg << 2) + r;
                yp[ybase + (size_t)orow * HW] = acc[fi][fj][r];
            }
    }
}

// ---------------------------------------------------------------------------
// K2: FUSED psum-reduce + BN stats + scale/shift/ReLU + row-center.
//     (round-13/14 verified)
// ---------------------------------------------------------------------------
__global__ __launch_bounds__(256) void k_bnc(const float* __restrict__ ps,
                                             float* __restrict__ z,
                                             const float* __restrict__ gamma,
                                             const float* __restrict__ beta) {
    const int o = blockIdx.x;
    const int tid = threadIdx.x;
    __shared__ float yb[64][200];     // 200-float rows: 16B-aligned, 51.2 KB
    __shared__ float rs[4], rs2[4];
    __shared__ float s_sc, s_sh;

    float s = 0.f, s2 = 0.f;
    for (int t = tid; t < 64 * 49; t += 256) {
        const int b = t / 49, c = t - b * 49;
        const size_t idx = ((size_t)b * O + o) * HW + c * 4;
        float4 a = *(const float4*)&ps[idx];
        const float4 p1 = *(const float4*)&ps[YN + idx];
        const float4 p2 = *(const float4*)&ps[2 * YN + idx];
        const float4 p3 = *(const float4*)&ps[3 * YN + idx];
        a.x += p1.x + p2.x + p3.x; a.y += p1.y + p2.y + p3.y;
        a.z += p1.z + p2.z + p3.z; a.w += p1.w + p2.w + p3.w;
        *(float4*)&yb[b][c * 4] = a;
        s  += (a.x + a.y) + (a.z + a.w);
        s2 += (a.x * a.x + a.y * a.y) + (a.z * a.z + a.w * a.w);
    }
    #pragma unroll
    for (int msk = 32; msk; msk >>= 1) {
        s  += __shfl_xor(s,  msk);
        s2 += __shfl_xor(s2, msk);
    }
    if ((tid & 63) == 0) { rs[tid >> 6] = s; rs2[tid >> 6] = s2; }
    __syncthreads();                      // yb complete + rs/rs2 ready
    if (tid == 0) {
        const float N = (float)(B * HW);
        const float ts  = rs[0] + rs[1] + rs[2] + rs[3];
        const float ts2 = rs2[0] + rs2[1] + rs2[2] + rs2[3];
        const float mean = ts / N;
        const float var  = ts2 / N - mean * mean;
        const float sc = gamma[o] * rsqrtf(var + 1e-5f);
        s_sc = sc;
        s_sh = beta[o] - mean * sc;
    }
    __syncthreads();
    const float sc = s_sc, sh = s_sh;

    // phase 2: wave w centers rows b = w*16 .. w*16+15
    const int lane = tid & 63, w = tid >> 6;
    for (int rr = 0; rr < 16; ++rr) {
        const int b = w * 16 + rr;
        float vals[4];
        float rsum = 0.f;
        #pragma unroll
        for (int q = 0; q < 4; ++q) {
            const int m = q * 64 + lane;
            float v = 0.f;
            if (m < HW) v = fmaxf(fmaf(yb[b][m], sc, sh), 0.f);
            vals[q] = v; rsum += v;
        }
        #pragma unroll
        for (int msk = 32; msk; msk >>= 1) rsum += __shfl_xor(rsum, msk);
        const float mean = rsum / (float)HW;
        float* zr = &z[((size_t)b * O + o) * HW];
        #pragma unroll
        for (int q = 0; q < 4; ++q) {
            const int m = q * 64 + lane;
            if (m < HW) zr[m] = vals[q] - mean;
        }
    }
}

// ---------------------------------------------------------------------------
// K4: cov[b] = zc zc^T / M.  FP32 accumulation (round-11/12 verified).
// ---------------------------------------------------------------------------
__global__ __launch_bounds__(256) void k_cov(const float* __restrict__ z,
                                             float* __restrict__ covf) {
    const int b = blockIdx.y;
    const int jt = blockIdx.x & 3, it = blockIdx.x >> 2;
    const int i0 = it * 64, j0 = jt * 64;
    const int tid = threadIdx.x;
    const int tn = tid & 15, tmq = tid >> 4;

    __shared__ float sA[28][68], sB[28][68];
    float acc[4][4] = {};
    const float* zb = &z[(size_t)b * D * HW];

    for (int k0 = 0; k0 < HW; k0 += 28) {
        #pragma unroll
        for (int q = 0; q < 7; ++q) {
            const int idx = tid + q * 256;
            const int r = idx / 28, kk = idx % 28;
            sA[kk][r] = zb[(size_t)(i0 + r) * HW + k0 + kk];
            sB[kk][r] = zb[(size_t)(j0 + r) * HW + k0 + kk];
        }
        __syncthreads();
        #pragma unroll
        for (int kk = 0; kk < 28; ++kk) {
            const float4 av = *reinterpret_cast<const float4*>(&sA[kk][tmq << 2]);
            const float4 bv = *reinterpret_cast<const float4*>(&sB[kk][tn << 2]);
            const float aa[4] = {av.x, av.y, av.z, av.w};
            const float bb[4] = {bv.x, bv.y, bv.z, bv.w};
            #pragma unroll
            for (int i = 0; i < 4; ++i)
                #pragma unroll
                for (int j = 0; j < 4; ++j)
                    acc[i][j] = fmaf(aa[i], bb[j], acc[i][j]);
        }
        __syncthreads();
    }
    const float inv = 1.0f / (float)HW;
    #pragma unroll
    for (int i = 0; i < 4; ++i)
        #pragma unroll
        for (int j = 0; j < 4; ++j)
            covf[(size_t)b * D * D + (size_t)(i0 + (tmq << 2) + i) * D
                 + j0 + (tn << 2) + j] = acc[i][j] * inv;
}

// ---------------------------------------------------------------------------
// K5: spectral-norm estimate, 6 power iterations on fp32 cov.
// ---------------------------------------------------------------------------
__global__ __launch_bounds__(256) void k_lmax(const float* __restrict__ covf,
                                              double* __restrict__ cn) {
    const int b = blockIdx.x;
    const int tid = threadIdx.x;
    const float* A = &covf[(size_t)b * 65536];
    __shared__ float vs[256];
    __shared__ float red[4];
    vs[tid] = 1.f;
    __syncthreads();
    float lam = 1.f;
    for (int it = 0; it < 6; ++it) {
        float u0 = 0.f, u1 = 0.f, u2 = 0.f, u3 = 0.f;
        #pragma unroll 8
        for (int k = 0; k < D; k += 4) {
            u0 = fmaf(A[(size_t)(k + 0) * D + tid], vs[k + 0], u0);
            u1 = fmaf(A[(size_t)(k + 1) * D + tid], vs[k + 1], u1);
            u2 = fmaf(A[(size_t)(k + 2) * D + tid], vs[k + 2], u2);
            u3 = fmaf(A[(size_t)(k + 3) * D + tid], vs[k + 3], u3);
        }
        const float uu = (u0 + u1) + (u2 + u3);
        float sq = uu * uu;
        #pragma unroll
        for (int msk = 32; msk; msk >>= 1) sq += __shfl_xor(sq, msk);
        __syncthreads();
        if ((tid & 63) == 0) red[tid >> 6] = sq;
        __syncthreads();
        const float nrm = sqrtf(red[0] + red[1] + red[2] + red[3]) + 1e-30f;
        lam = nrm;
        vs[tid] = uu / nrm;
        __syncthreads();
    }
    if (tid == 0) cn[b] = (lam > 1e-30f) ? 1.25 * (double)lam : 1.0;
}

// ---------------------------------------------------------------------------
// K6: Y0 planes = bf16-split (covf/c + 1e-7 I), FULL matrix.  Vectorized.
// ---------------------------------------------------------------------------
__global__ __launch_bounds__(256) void k_init(const float* __restrict__ covf,
                                              const double* __restrict__ cn,
                                              u16* __restrict__ Yh,
                                              u16* __restrict__ Yl) {
    const size_t e4 = ((size_t)blockIdx.x * 256 + threadIdx.x) * 4;
    const int b = (int)(e4 >> 16);
    const int ij = (int)(e4 & 65535);
    const int i = ij >> 8, j0_ = ij & 255;       // 4 elems within one row
    const float4 cv = *(const float4*)&covf[e4];
    const float inv = 1.f / (float)cn[b];
    float f[4] = {cv.x * inv, cv.y * inv, cv.z * inv, cv.w * inv};
    const int dk = i - j0_;
    if (dk >= 0 && dk < 4) f[dk] += 1e-7f;
    u16x4 h4, l4;
    #pragma unroll
    for (int k = 0; k < 4; ++k) {
        const u16 h = f2bf(f[k]);
        h4[k] = h;
        l4[k] = f2bf(f[k] - bf2f(h));
    }
    *(u16x4*)&Yh[e4] = h4;
    *(u16x4*)&Yl[e4] = l4;
}

// ---------------------------------------------------------------------------
// K7: bf16-MFMA symmetric gemm on hi/lo planes.
//     Block = 4 waves, 128x64 tile, wave 64x32.  K-STEP 32 (same k-chunk
//     order as K-64 -> bit-identical accumulation), LDS stride 40 (16-B
//     aligned rows): staging 30 KB -> 4-5 blocks/CU by LDS, with
//     launch_bounds (256,2) so the register allocator is UNCONSTRAINED
//     (round-9's failure was the (256,5) reg cap -> spills, not K-32).
//     Register prefetch, B read via symmetry, direct scalar-store epilogue,
//     MODE-1 A-loads hoisted.  Full 8-tile grid (512/1024), XCD-affine.
//       MODE 1: C = (15I - 10*A + 3*A*B)/8 = q(A) (A==B)
//       MODE 2: C = A*B
//       MODE 3: out[tri] = sqrt(cn)*(A*B) upper triangle
// ---------------------------------------------------------------------------
template <int MODE, int FUSED>
__global__ __launch_bounds__(256, 2) void k_mgemm(
        const u16* __restrict__ A0h, const u16* __restrict__ A0l,
        const u16* __restrict__ B0h, const u16* __restrict__ B0l,
        u16* __restrict__ C0h, u16* __restrict__ C0l,
        const u16* __restrict__ A1h, const u16* __restrict__ A1l,
        const u16* __restrict__ B1h, const u16* __restrict__ B1l,
        u16* __restrict__ C1h, u16* __restrict__ C1l,
        const double* __restrict__ cn, float* __restrict__ outp) {
    const int orig = blockIdx.x;
    const int xcd  = orig & 7;
    const int s    = orig >> 3;
    int batch, tile, opz;
    if (FUSED) {                       // 1024 blocks: s 0..127
        const int bl  = s >> 4;        // 0..7
        const int opq = s & 15;
        opz  = opq >> 3;
        tile = opq & 7;
        batch = xcd * 8 + bl;
    } else {                           // 512 blocks: s 0..63
        opz = 0;
        batch = xcd * 8 + (s >> 3);
        tile = s & 7;
    }

    const u16 *Ah, *Al, *Bh, *Bl;
    u16 *Ch, *Cl;
    if (opz == 0) { Ah = A0h; Al = A0l; Bh = B0h; Bl = B0l; Ch = C0h; Cl = C0l; }
    else          { Ah = A1h; Al = A1l; Bh = B1h; Bl = B1l; Ch = C1h; Cl = C1l; }

    const int i0 = (tile >> 2) * 128, j0 = (tile & 3) * 64;
    const size_t boff = (size_t)batch * 65536;
    Ah += boff; Al += boff; Bh += boff; Bl += boff; Ch += boff; Cl += boff;

    const int tid = threadIdx.x;
    __shared__ u16 sA[2][128][40];   // [plane][row][k]  20 KB
    __shared__ u16 sB[2][64][40];    // [plane][row][k]  10 KB

    const int rA = tid >> 1, khA = (tid & 1) * 16;
    const u16* gAh = Ah + (size_t)(i0 + rA) * 256 + khA;
    const u16* gAl = Al + (size_t)(i0 + rA) * 256 + khA;
    // B read as rows of its symmetric self: B[k][j] == B[j][k]
    const int rB = tid >> 2, khB = (tid & 3) * 8;
    const u16* gBh = Bh + (size_t)(j0 + rB) * 256 + khB;
    const u16* gBl = Bl + (size_t)(j0 + rB) * 256 + khB;

    const int lane = tid & 63, w = tid >> 6;
    const int wr = w >> 1, wc = w & 1;
    const int lr = lane & 15, lg = lane >> 4, ko = lg << 3;
    const int orow = wr * 64 + (lg << 2);   // + fi*16 + r
    const int ocol = wc * 32 + lr;          // + fj*16

    // MODE-1: hoist the A-tile values this thread needs for q(A), so the
    // scattered reads issue before the K-loop and their latency hides.
    float xv[4][4][2];
    if (MODE == 1) {
        #pragma unroll
        for (int fi = 0; fi < 4; ++fi)
            #pragma unroll
            for (int r = 0; r < 4; ++r) {
                const int gi = i0 + orow + fi * 16 + r;
                #pragma unroll
                for (int fj = 0; fj < 2; ++fj) {
                    const size_t xo = (size_t)gi * 256 + j0 + ocol + fj * 16;
                    xv[fi][r][fj] = bf2f(Ah[xo]) + bf2f(Al[xo]);
                }
            }
    }

    f32x4 acc[4][2] = {};

    u16x8 pAh[2], pAl[2], pBh, pBl;
    auto g_load = [&](int kb) {
        pAh[0] = *(const u16x8*)&gAh[kb];
        pAh[1] = *(const u16x8*)&gAh[kb + 8];
        pAl[0] = *(const u16x8*)&gAl[kb];
        pAl[1] = *(const u16x8*)&gAl[kb + 8];
        pBh = *(const u16x8*)&gBh[kb];
        pBl = *(const u16x8*)&gBl[kb];
    };
    auto s_store = [&]() {
        *(u16x8*)&sA[0][rA][khA]     = pAh[0];
        *(u16x8*)&sA[0][rA][khA + 8] = pAh[1];
        *(u16x8*)&sA[1][rA][khA]     = pAl[0];
        *(u16x8*)&sA[1][rA][khA + 8] = pAl[1];
        *(u16x8*)&sB[0][rB][khB]     = pBh;
        *(u16x8*)&sB[1][rB][khB]     = pBl;
    };
    auto compute = [&]() {
        u16x8 fah[4], fal[4], fbh[2], fbl[2];
        #pragma unroll
        for (int f = 0; f < 4; ++f) {
            fah[f] = *(const u16x8*)&sA[0][wr * 64 + f * 16 + lr][ko];
            fal[f] = *(const u16x8*)&sA[1][wr * 64 + f * 16 + lr][ko];
        }
        #pragma unroll
        for (int f = 0; f < 2; ++f) {
            fbh[f] = *(const u16x8*)&sB[0][wc * 32 + f * 16 + lr][ko];
            fbl[f] = *(const u16x8*)&sB[1][wc * 32 + f * 16 + lr][ko];
        }
        #pragma unroll
        for (int fi = 0; fi < 4; ++fi)
            #pragma unroll
            for (int fj = 0; fj < 2; ++fj) {
                acc[fi][fj] = mm_bf16(fah[fi], fbh[fj], acc[fi][fj]);
                acc[fi][fj] = mm_bf16(fah[fi], fbl[fj], acc[fi][fj]);
                acc[fi][fj] = mm_bf16(fal[fi], fbh[fj], acc[fi][fj]);
            }
    };

    g_load(0);
    for (int st = 0; st < 8; ++st) {
        __syncthreads();                 // previous K-step fully consumed
        s_store();
        __syncthreads();                 // buffer ready
        if (st < 7) g_load((st + 1) * 32);
        compute();
    }

    // ---- epilogue ----
    if (MODE == 3) {
        const double sc = sqrt(cn[batch]);
        #pragma unroll
        for (int fi = 0; fi < 4; ++fi)
            #pragma unroll
            for (int r = 0; r < 4; ++r) {
                const int gi = i0 + orow + fi * 16 + r;
                const size_t rowoff = (size_t)gi * D - ((size_t)gi * (gi - 1)) / 2;
                #pragma unroll
                for (int fj = 0; fj < 2; ++fj) {
                    const int gj = j0 + ocol + fj * 16;
                    if (gj >= gi)
                        outp[(size_t)batch * TRI + rowoff + (gj - gi)] =
                            (float)(sc * (double)acc[fi][fj][r]);
                }
            }
        return;
    }

    #pragma unroll
    for (int fi = 0; fi < 4; ++fi)
        #pragma unroll
        for (int r = 0; r < 4; ++r) {
            const int gi = i0 + orow + fi * 16 + r;
            #pragma unroll
            for (int fj = 0; fj < 2; ++fj) {
                const int gj = j0 + ocol + fj * 16;
                float v = acc[fi][fj][r];
                if (MODE == 1) {
                    v = (((gi == gj) ? 15.0f : 0.0f)
                         - 10.0f * xv[fi][r][fj] + 3.0f * v) * 0.125f;
                }
                const u16 h = f2bf(v);
                const u16 lo = f2bf(v - bf2f(h));
                const size_t co = (size_t)gi * 256 + gj;
                Ch[co] = h;
                Cl[co] = lo;
            }
        }
}

// ---------------------------------------------------------------------------
extern "C" void kernel_launch(void* const* d_in, const int* in_sizes, int n_in,
                              void* d_out, int out_size, void* d_ws, size_t ws_size,
                              hipStream_t stream) {
    const float* x     = (const float*)d_in[0];
    const float* W     = (const float*)d_in[1];
    const float* gamma = (const float*)d_in[2];
    const float* beta  = (const float*)d_in[3];
    float* out = (float*)d_out;

    char* ws = (char*)d_ws;
    size_t off = 0;
    auto alloc = [&](size_t bytes) -> void* {
        void* p = ws + off;
        off += (bytes + 255) & ~(size_t)255;
        return p;
    };
    float*  y    = (float*)alloc(YN * sizeof(float));
    float*  covf = (float*)alloc(NELEM * sizeof(float));
    double* cn   = (double*)alloc(B * sizeof(double));
    u16*    Wh   = (u16*)alloc((size_t)O * CIN * sizeof(u16));
    u16*    Wl   = (u16*)alloc((size_t)O * CIN * sizeof(u16));
    // 12 bf16 planes for the Z-free Newton-Schulz chain (Y/M ping-pong, R, U)
    u16* pl = (u16*)alloc(12 * NELEM * sizeof(u16));
    if (off > ws_size) return;
    u16 *YAh = pl,             *YAl = pl + NELEM;
    u16 *YBh = pl + 2 * NELEM, *YBl = pl + 3 * NELEM;
    u16 *MAh = pl + 4 * NELEM, *MAl = pl + 5 * NELEM;
    u16 *MBh = pl + 6 * NELEM, *MBl = pl + 7 * NELEM;
    u16 *Rh  = pl + 8 * NELEM, *Rl  = pl + 9 * NELEM;
    u16 *Uh  = pl + 10 * NELEM,*Ul  = pl + 11 * NELEM;
    float* psum = (float*)pl;   // conv partials alias the plane block (dead until k_init)

    k_wsplit <<<(O * CIN) / 256, 256, 0, stream>>>(W, Wh, Wl);
    k_conv   <<<784, 256, 0, stream>>>(x, Wh, Wl, psum);
    k_bnc    <<<O, 256, 0, stream>>>(psum, y, gamma, beta);
    k_cov    <<<dim3(16, B), 256, 0, stream>>>(y, covf);
    k_lmax   <<<B, 256, 0, stream>>>(covf, cn);
    k_init   <<<(int)(NELEM / 1024), 256, 0, stream>>>(covf, cn, YAh, YAl);

    // Z-free coupled Newton-Schulz: M = Z*Y tracked directly.
    //   R = q(M); Y' = Y*R; M' = R*(M*R).
    // ---- iteration 0 (M0 == Y0):
    k_mgemm<1, 0><<<512, 256, 0, stream>>>(YAh, YAl, YAh, YAl, Rh, Rl,
                                           YAh, YAl, YAh, YAl, Rh, Rl, cn, out);
    k_mgemm<2, 0><<<512, 256, 0, stream>>>(YAh, YAl, Rh, Rl, YBh, YBl,
                                           YAh, YAl, Rh, Rl, YBh, YBl, cn, out);
    k_mgemm<2, 0><<<512, 256, 0, stream>>>(Rh, Rl, YBh, YBl, MBh, MBl,
                                           Rh, Rl, YBh, YBl, MBh, MBl, cn, out);

    u16 *Ych = YBh, *Ycl = YBl, *Yah = YAh, *Yal = YAl;
    u16 *Mch = MBh, *Mcl = MBl, *Mah = MAh, *Mal = MAl;
    for (int itq = 0; itq < NQ_COUPLED; ++itq) {
        // R = q(Mc)
        k_mgemm<1, 0><<<512, 256, 0, stream>>>(Mch, Mcl, Mch, Mcl, Rh, Rl,
                                               Mch, Mcl, Mch, Mcl, Rh, Rl, cn, out);
        // fused: Ya = Yc*R ; U = Mc*R
        k_mgemm<2, 1><<<1024, 256, 0, stream>>>(Ych, Ycl, Rh, Rl, Yah, Yal,
                                                Mch, Mcl, Rh, Rl, Uh, Ul, cn, out);
        // Ma = R*U = R*Mc*R
        k_mgemm<2, 0><<<512, 256, 0, stream>>>(Rh, Rl, Uh, Ul, Mah, Mal,
                                               Rh, Rl, Uh, Ul, Mah, Mal, cn, out);
        u16* t;
        t = Ych; Ych = Yah; Yah = t;  t = Ycl; Ycl = Yal; Yal = t;
        t = Mch; Mch = Mah; Mah = t;  t = Mcl; Mcl = Mal; Mal = t;
    }
    // final: R = q(Mc); out = sqrt(cn) * (Yc*R) upper triangle
    k_mgemm<1, 0><<<512, 256, 0, stream>>>(Mch, Mcl, Mch, Mcl, Rh, Rl,
                                           Mch, Mcl, Mch, Mcl, Rh, Rl, cn, out);
    k_mgemm<3, 0><<<512, 256, 0, stream>>>(Ych, Ycl, Rh, Rl, Uh, Ul,
                                           Ych, Ycl, Rh, Rl, Uh, Ul, cn, out);
}

// Round 16
// 459.966 us; speedup vs baseline: 1.0109x; 1.0109x over previous
//
#include <hip/hip_runtime.h>
#include <hip/hip_bf16.h>

// Problem constants
static constexpr int B   = 64;
static constexpr int CIN = 2048;
static constexpr int O   = 256;    // out channels = d
static constexpr int HW  = 196;    // 14*14 = M
static constexpr int D   = 256;    // matrix dim
static constexpr int TRI = 32896;  // D*(D+1)/2
static constexpr int NQ_COUPLED = 5; // coupled iters AFTER the identity iter0
static constexpr size_t NELEM = (size_t)B * D * D;   // 4,194,304
static constexpr size_t YN    = (size_t)B * O * HW;  // 3,211,264

typedef unsigned short u16;
typedef unsigned short u16x4 __attribute__((ext_vector_type(4)));
typedef unsigned short u16x8 __attribute__((ext_vector_type(8)));
typedef __bf16         bf16x8 __attribute__((ext_vector_type(8)));
typedef float          f32x4 __attribute__((ext_vector_type(4)));

static __device__ __forceinline__ float bf2f(u16 h) {
    return __uint_as_float(((unsigned int)h) << 16);
}
// native RNE split: bit-identical to the old manual f2bf pair, but lowers
// to v_cvt_pk_bf16_f32 (round-14 verified: VALUBusy 16->10% in k_conv).
static __device__ __forceinline__ void bfsplit(float v, u16& h, u16& l) {
    const __bf16 hb = (__bf16)v;
    const __bf16 lb = (__bf16)(v - (float)hb);
    h = __builtin_bit_cast(u16, hb);
    l = __builtin_bit_cast(u16, lb);
}
static __device__ __forceinline__ f32x4 mm_bf16(u16x8 a, u16x8 b, f32x4 c) {
    return __builtin_amdgcn_mfma_f32_16x16x32_bf16(
        __builtin_bit_cast(bf16x8, a), __builtin_bit_cast(bf16x8, b), c, 0, 0, 0);
}

// ---------------------------------------------------------------------------
// K0: split W fp32 -> bf16 (Wh, Wl) planes, once
// ---------------------------------------------------------------------------
__global__ __launch_bounds__(256) void k_wsplit(const float* __restrict__ W,
                                                u16* __restrict__ Wh,
                                                u16* __restrict__ Wl) {
    const size_t i = (size_t)blockIdx.x * 256 + threadIdx.x;
    u16 h, l;
    bfsplit(W[i], h, l);
    Wh[i] = h;
    Wl[i] = l;
}

// ---------------------------------------------------------------------------
// K1: conv = W(256x2048) * X(2048x12544), bf16 2-plane split MFMA.
//     128x128 tile per block, 4 waves, each wave a 64x64 register tile.
//     K-split 4 (784 blocks), K-step 32, LDS stride 40 (80 B rows, 16-B
//     aligned).  Native __bf16 casts (round-14 verified).
// ---------------------------------------------------------------------------
__global__ __launch_bounds__(256, 3) void k_conv(const float* __restrict__ x,
                                                 const u16* __restrict__ Wh,
                                                 const u16* __restrict__ Wl,
                                                 float* __restrict__ psum) {
    const int l   = blockIdx.x;
    const int xcd = l & 7, u = l >> 3;        // u 0..97
    const int q   = xcd * 98 + u;             // 0..783, XCD-affine
    const int ks  = q & 3;
    const int t2  = q >> 2;                   // 0..195
    const int ot  = t2 & 1, gt = t2 >> 1;     // gt 0..97
    const int o0  = ot * 128;
    const int cbase = ks * 512;
    float* yp = psum + (size_t)ks * YN;

    const int tid = threadIdx.x;

    __shared__ u16 sW[2][128][40], sX[2][128][40];   // [plane][row][k], 40 KB

    // per-thread X staging column (constant per thread)
    const int colX  = tid & 127;
    const int chalf = (tid >> 7) * 16;        // c-offset 0 or 16
    const int gX = gt * 128 + colX;
    const int bX = gX / 196;
    const int mX = gX - bX * 196;
    const size_t xbase = (size_t)bX * (CIN * HW) + mX;   // + c*HW

    // W staging: thread -> row, k-half (16 elems)
    const int rW = tid >> 1, kq = (tid & 1) * 16;
    const u16* gWh = Wh + (size_t)(o0 + rW) * CIN + cbase + kq;
    const u16* gWl = Wl + (size_t)(o0 + rW) * CIN + cbase + kq;

    const int lane = tid & 63, w = tid >> 6;
    const int wr = w >> 1, wc = w & 1;
    const int lr = lane & 15, lg = lane >> 4, ko = lg << 3;

    f32x4 acc[4][4] = {};

    u16x8 pWh[2], pWl[2];
    float pX[16];
    u16x4 cXh[4], cXl[4];

    auto loadW = [&](int kb) {
        #pragma unroll
        for (int qq = 0; qq < 2; ++qq) {
            pWh[qq] = *(const u16x8*)&gWh[kb + qq * 8];
            pWl[qq] = *(const u16x8*)&gWl[kb + qq * 8];
        }
    };
    auto loadX = [&](int kb) {
        #pragma unroll
        for (int i = 0; i < 16; ++i)
            pX[i] = x[xbase + (size_t)(cbase + kb + chalf + i) * HW];
    };
    auto convX = [&]() {
        #pragma unroll
        for (int i = 0; i < 16; i += 4) {
            u16x4 vh, vl;
            #pragma unroll
            for (int j = 0; j < 4; ++j) {
                u16 h, lo;
                bfsplit(pX[i + j], h, lo);
                vh[j] = h;
                vl[j] = lo;
            }
            cXh[i >> 2] = vh;
            cXl[i >> 2] = vl;
        }
    };
    auto storeWX = [&]() {
        #pragma unroll
        for (int qq = 0; qq < 2; ++qq) {
            *(u16x8*)&sW[0][rW][kq + qq * 8] = pWh[qq];
            *(u16x8*)&sW[1][rW][kq + qq * 8] = pWl[qq];
        }
        #pragma unroll
        for (int qq = 0; qq < 4; ++qq) {
            *(u16x4*)&sX[0][colX][chalf + qq * 4] = cXh[qq];
            *(u16x4*)&sX[1][colX][chalf + qq * 4] = cXl[qq];
        }
    };
    auto compute = [&]() {
        u16x8 fah[4], fal[4], fbh[4], fbl[4];
        #pragma unroll
        for (int f = 0; f < 4; ++f) {
            fah[f] = *(const u16x8*)&sW[0][wr * 64 + f * 16 + lr][ko];
            fal[f] = *(const u16x8*)&sW[1][wr * 64 + f * 16 + lr][ko];
            fbh[f] = *(const u16x8*)&sX[0][wc * 64 + f * 16 + lr][ko];
            fbl[f] = *(const u16x8*)&sX[1][wc * 64 + f * 16 + lr][ko];
        }
        #pragma unroll
        for (int fi = 0; fi < 4; ++fi)
            #pragma unroll
            for (int fj = 0; fj < 4; ++fj) {
                acc[fi][fj] = mm_bf16(fah[fi], fbh[fj], acc[fi][fj]);
                acc[fi][fj] = mm_bf16(fah[fi], fbl[fj], acc[fi][fj]);
                acc[fi][fj] = mm_bf16(fal[fi], fbh[fj], acc[fi][fj]);
            }
    };

    loadW(0); loadX(0); convX();
    for (int st = 0; st < 16; ++st) {
        __syncthreads();                  // all reads of previous K-step done
        storeWX();
        __syncthreads();                  // buffer ready
        if (st < 15) { loadW((st + 1) * 32); loadX((st + 1) * 32); }
        compute();
        if (st < 15) convX();
    }

    // epilogue: psum[ks][b][o][m]
    #pragma unroll
    for (int fj = 0; fj < 4; ++fj) {
        const int gcol = gt * 128 + wc * 64 + fj * 16 + lr;
        const int bb = gcol / 196;
        const int mm = gcol - bb * 196;
        const size_t ybase = (size_t)bb * (O * HW) + mm;
        #pragma unroll
        for (int fi = 0; fi < 4; ++fi)
            #pragma unroll
            for (int r = 0; r < 4; ++r) {
                const int orow = o0 + wr * 64 + fi * 16 + (lg << 2) + r;
                yp[ybase + (size_t)orow * HW] = acc[fi][fj][r];
            }
    }
}

// ---------------------------------------------------------------------------
// K2: FUSED psum-reduce + BN stats + scale/shift/ReLU + row-center.
//     (round-13/14 verified)
// ---------------------------------------------------------------------------
__global__ __launch_bounds__(256) void k_bnc(const float* __restrict__ ps,
                                             float* __restrict__ z,
                                             const float* __restrict__ gamma,
                                             const float* __restrict__ beta) {
    const int o = blockIdx.x;
    const int tid = threadIdx.x;
    __shared__ float yb[64][200];     // 200-float rows: 16B-aligned, 51.2 KB
    __shared__ float rs[4], rs2[4];
    __shared__ float s_sc, s_sh;

    float s = 0.f, s2 = 0.f;
    for (int t = tid; t < 64 * 49; t += 256) {
        const int b = t / 49, c = t - b * 49;
        const size_t idx = ((size_t)b * O + o) * HW + c * 4;
        float4 a = *(const float4*)&ps[idx];
        const float4 p1 = *(const float4*)&ps[YN + idx];
        const float4 p2 = *(const float4*)&ps[2 * YN + idx];
        const float4 p3 = *(const float4*)&ps[3 * YN + idx];
        a.x += p1.x + p2.x + p3.x; a.y += p1.y + p2.y + p3.y;
        a.z += p1.z + p2.z + p3.z; a.w += p1.w + p2.w + p3.w;
        *(float4*)&yb[b][c * 4] = a;
        s  += (a.x + a.y) + (a.z + a.w);
        s2 += (a.x * a.x + a.y * a.y) + (a.z * a.z + a.w * a.w);
    }
    #pragma unroll
    for (int msk = 32; msk; msk >>= 1) {
        s  += __shfl_xor(s,  msk);
        s2 += __shfl_xor(s2, msk);
    }
    if ((tid & 63) == 0) { rs[tid >> 6] = s; rs2[tid >> 6] = s2; }
    __syncthreads();                      // yb complete + rs/rs2 ready
    if (tid == 0) {
        const float N = (float)(B * HW);
        const float ts  = rs[0] + rs[1] + rs[2] + rs[3];
        const float ts2 = rs2[0] + rs2[1] + rs2[2] + rs2[3];
        const float mean = ts / N;
        const float var  = ts2 / N - mean * mean;
        const float sc = gamma[o] * rsqrtf(var + 1e-5f);
        s_sc = sc;
        s_sh = beta[o] - mean * sc;
    }
    __syncthreads();
    const float sc = s_sc, sh = s_sh;

    // phase 2: wave w centers rows b = w*16 .. w*16+15
    const int lane = tid & 63, w = tid >> 6;
    for (int rr = 0; rr < 16; ++rr) {
        const int b = w * 16 + rr;
        float vals[4];
        float rsum = 0.f;
        #pragma unroll
        for (int q = 0; q < 4; ++q) {
            const int m = q * 64 + lane;
            float v = 0.f;
            if (m < HW) v = fmaxf(fmaf(yb[b][m], sc, sh), 0.f);
            vals[q] = v; rsum += v;
        }
        #pragma unroll
        for (int msk = 32; msk; msk >>= 1) rsum += __shfl_xor(rsum, msk);
        const float mean = rsum / (float)HW;
        float* zr = &z[((size_t)b * O + o) * HW];
        #pragma unroll
        for (int q = 0; q < 4; ++q) {
            const int m = q * 64 + lane;
            if (m < HW) zr[m] = vals[q] - mean;
        }
    }
}

// ---------------------------------------------------------------------------
// K4: cov[b] = zc zc^T / M.  FP32 accumulation (round-11/12 verified).
// ---------------------------------------------------------------------------
__global__ __launch_bounds__(256) void k_cov(const float* __restrict__ z,
                                             float* __restrict__ covf) {
    const int b = blockIdx.y;
    const int jt = blockIdx.x & 3, it = blockIdx.x >> 2;
    const int i0 = it * 64, j0 = jt * 64;
    const int tid = threadIdx.x;
    const int tn = tid & 15, tmq = tid >> 4;

    __shared__ float sA[28][68], sB[28][68];
    float acc[4][4] = {};
    const float* zb = &z[(size_t)b * D * HW];

    for (int k0 = 0; k0 < HW; k0 += 28) {
        #pragma unroll
        for (int q = 0; q < 7; ++q) {
            const int idx = tid + q * 256;
            const int r = idx / 28, kk = idx % 28;
            sA[kk][r] = zb[(size_t)(i0 + r) * HW + k0 + kk];
            sB[kk][r] = zb[(size_t)(j0 + r) * HW + k0 + kk];
        }
        __syncthreads();
        #pragma unroll
        for (int kk = 0; kk < 28; ++kk) {
            const float4 av = *reinterpret_cast<const float4*>(&sA[kk][tmq << 2]);
            const float4 bv = *reinterpret_cast<const float4*>(&sB[kk][tn << 2]);
            const float aa[4] = {av.x, av.y, av.z, av.w};
            const float bb[4] = {bv.x, bv.y, bv.z, bv.w};
            #pragma unroll
            for (int i = 0; i < 4; ++i)
                #pragma unroll
                for (int j = 0; j < 4; ++j)
                    acc[i][j] = fmaf(aa[i], bb[j], acc[i][j]);
        }
        __syncthreads();
    }
    const float inv = 1.0f / (float)HW;
    #pragma unroll
    for (int i = 0; i < 4; ++i)
        #pragma unroll
        for (int j = 0; j < 4; ++j)
            covf[(size_t)b * D * D + (size_t)(i0 + (tmq << 2) + i) * D
                 + j0 + (tn << 2) + j] = acc[i][j] * inv;
}

// ---------------------------------------------------------------------------
// K5: spectral-norm estimate, 6 power iterations on fp32 cov.
// ---------------------------------------------------------------------------
__global__ __launch_bounds__(256) void k_lmax(const float* __restrict__ covf,
                                              double* __restrict__ cn) {
    const int b = blockIdx.x;
    const int tid = threadIdx.x;
    const float* A = &covf[(size_t)b * 65536];
    __shared__ float vs[256];
    __shared__ float red[4];
    vs[tid] = 1.f;
    __syncthreads();
    float lam = 1.f;
    for (int it = 0; it < 6; ++it) {
        float u0 = 0.f, u1 = 0.f, u2 = 0.f, u3 = 0.f;
        #pragma unroll 8
        for (int k = 0; k < D; k += 4) {
            u0 = fmaf(A[(size_t)(k + 0) * D + tid], vs[k + 0], u0);
            u1 = fmaf(A[(size_t)(k + 1) * D + tid], vs[k + 1], u1);
            u2 = fmaf(A[(size_t)(k + 2) * D + tid], vs[k + 2], u2);
            u3 = fmaf(A[(size_t)(k + 3) * D + tid], vs[k + 3], u3);
        }
        const float uu = (u0 + u1) + (u2 + u3);
        float sq = uu * uu;
        #pragma unroll
        for (int msk = 32; msk; msk >>= 1) sq += __shfl_xor(sq, msk);
        __syncthreads();
        if ((tid & 63) == 0) red[tid >> 6] = sq;
        __syncthreads();
        const float nrm = sqrtf(red[0] + red[1] + red[2] + red[3]) + 1e-30f;
        lam = nrm;
        vs[tid] = uu / nrm;
        __syncthreads();
    }
    if (tid == 0) cn[b] = (lam > 1e-30f) ? 1.25 * (double)lam : 1.0;
}

// ---------------------------------------------------------------------------
// K6: Y0 planes = bf16-split (covf/c + 1e-7 I), FULL matrix.  Vectorized,
//     native cast split.
// ---------------------------------------------------------------------------
__global__ __launch_bounds__(256) void k_init(const float* __restrict__ covf,
                                              const double* __restrict__ cn,
                                              u16* __restrict__ Yh,
                                              u16* __restrict__ Yl) {
    const size_t e4 = ((size_t)blockIdx.x * 256 + threadIdx.x) * 4;
    const int b = (int)(e4 >> 16);
    const int ij = (int)(e4 & 65535);
    const int i = ij >> 8, j0_ = ij & 255;       // 4 elems within one row
    const float4 cv = *(const float4*)&covf[e4];
    const float inv = 1.f / (float)cn[b];
    float f[4] = {cv.x * inv, cv.y * inv, cv.z * inv, cv.w * inv};
    const int dk = i - j0_;
    if (dk >= 0 && dk < 4) f[dk] += 1e-7f;
    u16x4 h4, l4;
    #pragma unroll
    for (int k = 0; k < 4; ++k) {
        u16 h, lo;
        bfsplit(f[k], h, lo);
        h4[k] = h;
        l4[k] = lo;
    }
    *(u16x4*)&Yh[e4] = h4;
    *(u16x4*)&Yl[e4] = l4;
}

// ---------------------------------------------------------------------------
// K7: bf16-MFMA symmetric gemm on hi/lo planes (round-14 proven: 460us cfg;
//     round-15's K-32 variant regressed — reverted).
//     Block = 4 waves, 128x64 tile, wave 64x32; K-step 64, single LDS
//     buffer + register prefetch; B read via symmetry (row reads).
//     Full 8-tile grid (512 non-fused / 1024 fused).  XCD-affine batches.
//     MODE-1's A-tile re-read hoisted BEFORE the K-loop.
//     LDS row stride 68: 51 KB -> 3 blocks/CU (VGPR unconstrained).
//     Epilogue bf16-split via native casts (bit-identical, fewer VALU).
//       MODE 1: C = (15I - 10*A + 3*A*B)/8 = q(A) (A==B)
//       MODE 2: C = A*B
//       MODE 3: out[tri] = sqrt(cn)*(A*B) upper triangle
// ---------------------------------------------------------------------------
template <int MODE, int FUSED>
__global__ __launch_bounds__(256, 2) void k_mgemm(
        const u16* __restrict__ A0h, const u16* __restrict__ A0l,
        const u16* __restrict__ B0h, const u16* __restrict__ B0l,
        u16* __restrict__ C0h, u16* __restrict__ C0l,
        const u16* __restrict__ A1h, const u16* __restrict__ A1l,
        const u16* __restrict__ B1h, const u16* __restrict__ B1l,
        u16* __restrict__ C1h, u16* __restrict__ C1l,
        const double* __restrict__ cn, float* __restrict__ outp) {
    const int orig = blockIdx.x;
    const int xcd  = orig & 7;
    const int s    = orig >> 3;
    int batch, tile, opz;
    if (FUSED) {                       // 1024 blocks: s 0..127
        const int bl  = s >> 4;        // 0..7
        const int opq = s & 15;
        opz  = opq >> 3;
        tile = opq & 7;
        batch = xcd * 8 + bl;
    } else {                           // 512 blocks: s 0..63
        opz = 0;
        batch = xcd * 8 + (s >> 3);
        tile = s & 7;
    }

    const u16 *Ah, *Al, *Bh, *Bl;
    u16 *Ch, *Cl;
    if (opz == 0) { Ah = A0h; Al = A0l; Bh = B0h; Bl = B0l; Ch = C0h; Cl = C0l; }
    else          { Ah = A1h; Al = A1l; Bh = B1h; Bl = B1l; Ch = C1h; Cl = C1l; }

    const int i0 = (tile >> 2) * 128, j0 = (tile & 3) * 64;
    const size_t boff = (size_t)batch * 65536;
    Ah += boff; Al += boff; Bh += boff; Bl += boff; Ch += boff; Cl += boff;

    const int tid = threadIdx.x;
    __shared__ u16 sA[2][128][68];   // [plane][row][k]  34 KB
    __shared__ u16 sB[2][64][68];    // [plane][row][k]  17 KB

    const int rA = tid >> 1, khA = (tid & 1) * 32;
    const u16* gAh = Ah + (size_t)(i0 + rA) * 256 + khA;
    const u16* gAl = Al + (size_t)(i0 + rA) * 256 + khA;
    // B read as rows of its symmetric self: B[k][j] == B[j][k]
    const int rB = tid >> 2, khB = (tid & 3) * 16;
    const u16* gBh = Bh + (size_t)(j0 + rB) * 256 + khB;
    const u16* gBl = Bl + (size_t)(j0 + rB) * 256 + khB;

    const int lane = tid & 63, w = tid >> 6;
    const int wr = w >> 1, wc = w & 1;
    const int lr = lane & 15, lg = lane >> 4, ko = lg << 3;
    const int orow = wr * 64 + (lg << 2);   // + fi*16 + r
    const int ocol = wc * 32 + lr;          // + fj*16

    // MODE-1: hoist the A-tile values this thread needs for q(A), so the
    // scattered reads issue before the K-loop and their latency hides.
    float xv[4][4][2];
    if (MODE == 1) {
        #pragma unroll
        for (int fi = 0; fi < 4; ++fi)
            #pragma unroll
            for (int r = 0; r < 4; ++r) {
                const int gi = i0 + orow + fi * 16 + r;
                #pragma unroll
                for (int fj = 0; fj < 2; ++fj) {
                    const size_t xo = (size_t)gi * 256 + j0 + ocol + fj * 16;
                    xv[fi][r][fj] = bf2f(Ah[xo]) + bf2f(Al[xo]);
                }
            }
    }

    f32x4 acc[4][2] = {};

    u16x8 pAh[4], pAl[4], pBh[2], pBl[2];
    auto g_load = [&](int kb) {
        #pragma unroll
        for (int qq = 0; qq < 4; ++qq) {
            pAh[qq] = *(const u16x8*)&gAh[kb + qq * 8];
            pAl[qq] = *(const u16x8*)&gAl[kb + qq * 8];
        }
        #pragma unroll
        for (int qq = 0; qq < 2; ++qq) {
            pBh[qq] = *(const u16x8*)&gBh[kb + qq * 8];
            pBl[qq] = *(const u16x8*)&gBl[kb + qq * 8];
        }
    };
    auto s_store = [&]() {
        #pragma unroll
        for (int qq = 0; qq < 4; ++qq) {
            *(u16x8*)&sA[0][rA][khA + qq * 8] = pAh[qq];
            *(u16x8*)&sA[1][rA][khA + qq * 8] = pAl[qq];
        }
        #pragma unroll
        for (int qq = 0; qq < 2; ++qq) {
            *(u16x8*)&sB[0][rB][khB + qq * 8] = pBh[qq];
            *(u16x8*)&sB[1][rB][khB + qq * 8] = pBl[qq];
        }
    };
    auto compute = [&]() {
        #pragma unroll
        for (int kr = 0; kr < 2; ++kr) {
            const int kk = kr * 32 + ko;
            u16x8 fah[4], fal[4], fbh[2], fbl[2];
            #pragma unroll
            for (int f = 0; f < 4; ++f) {
                fah[f] = *(const u16x8*)&sA[0][wr * 64 + f * 16 + lr][kk];
                fal[f] = *(const u16x8*)&sA[1][wr * 64 + f * 16 + lr][kk];
            }
            #pragma unroll
            for (int f = 0; f < 2; ++f) {
                fbh[f] = *(const u16x8*)&sB[0][wc * 32 + f * 16 + lr][kk];
                fbl[f] = *(const u16x8*)&sB[1][wc * 32 + f * 16 + lr][kk];
            }
            #pragma unroll
            for (int fi = 0; fi < 4; ++fi)
                #pragma unroll
                for (int fj = 0; fj < 2; ++fj) {
                    acc[fi][fj] = mm_bf16(fah[fi], fbh[fj], acc[fi][fj]);
                    acc[fi][fj] = mm_bf16(fah[fi], fbl[fj], acc[fi][fj]);
                    acc[fi][fj] = mm_bf16(fal[fi], fbh[fj], acc[fi][fj]);
                }
        }
    };

    g_load(0);
    for (int st = 0; st < 4; ++st) {
        __syncthreads();                 // previous K-step fully consumed
        s_store();
        __syncthreads();                 // buffer ready
        if (st < 3) g_load((st + 1) * 64);
        compute();
    }

    // ---- epilogue ----
    if (MODE == 3) {
        const double sc = sqrt(cn[batch]);
        #pragma unroll
        for (int fi = 0; fi < 4; ++fi)
            #pragma unroll
            for (int r = 0; r < 4; ++r) {
                const int gi = i0 + orow + fi * 16 + r;
                const size_t rowoff = (size_t)gi * D - ((size_t)gi * (gi - 1)) / 2;
                #pragma unroll
                for (int fj = 0; fj < 2; ++fj) {
                    const int gj = j0 + ocol + fj * 16;
                    if (gj >= gi)
                        outp[(size_t)batch * TRI + rowoff + (gj - gi)] =
                            (float)(sc * (double)acc[fi][fj][r]);
                }
            }
        return;
    }

    #pragma unroll
    for (int fi = 0; fi < 4; ++fi)
        #pragma unroll
        for (int r = 0; r < 4; ++r) {
            const int gi = i0 + orow + fi * 16 + r;
            #pragma unroll
            for (int fj = 0; fj < 2; ++fj) {
                const int gj = j0 + ocol + fj * 16;
                float v = acc[fi][fj][r];
                if (MODE == 1) {
                    v = (((gi == gj) ? 15.0f : 0.0f)
                         - 10.0f * xv[fi][r][fj] + 3.0f * v) * 0.125f;
                }
                u16 h, lo;
                bfsplit(v, h, lo);
                const size_t co = (size_t)gi * 256 + gj;
                Ch[co] = h;
                Cl[co] = lo;
            }
        }
}

// ---------------------------------------------------------------------------
extern "C" void kernel_launch(void* const* d_in, const int* in_sizes, int n_in,
                              void* d_out, int out_size, void* d_ws, size_t ws_size,
                              hipStream_t stream) {
    const float* x     = (const float*)d_in[0];
    const float* W     = (const float*)d_in[1];
    const float* gamma = (const float*)d_in[2];
    const float* beta  = (const float*)d_in[3];
    float* out = (float*)d_out;

    char* ws = (char*)d_ws;
    size_t off = 0;
    auto alloc = [&](size_t bytes) -> void* {
        void* p = ws + off;
        off += (bytes + 255) & ~(size_t)255;
        return p;
    };
    float*  y    = (float*)alloc(YN * sizeof(float));
    float*  covf = (float*)alloc(NELEM * sizeof(float));
    double* cn   = (double*)alloc(B * sizeof(double));
    u16*    Wh   = (u16*)alloc((size_t)O * CIN * sizeof(u16));
    u16*    Wl   = (u16*)alloc((size_t)O * CIN * sizeof(u16));
    // 12 bf16 planes for the Z-free Newton-Schulz chain (Y/M ping-pong, R, U)
    u16* pl = (u16*)alloc(12 * NELEM * sizeof(u16));
    if (off > ws_size) return;
    u16 *YAh = pl,             *YAl = pl + NELEM;
    u16 *YBh = pl + 2 * NELEM, *YBl = pl + 3 * NELEM;
    u16 *MAh = pl + 4 * NELEM, *MAl = pl + 5 * NELEM;
    u16 *MBh = pl + 6 * NELEM, *MBl = pl + 7 * NELEM;
    u16 *Rh  = pl + 8 * NELEM, *Rl  = pl + 9 * NELEM;
    u16 *Uh  = pl + 10 * NELEM,*Ul  = pl + 11 * NELEM;
    float* psum = (float*)pl;   // conv partials alias the plane block (dead until k_init)

    k_wsplit <<<(O * CIN) / 256, 256, 0, stream>>>(W, Wh, Wl);
    k_conv   <<<784, 256, 0, stream>>>(x, Wh, Wl, psum);
    k_bnc    <<<O, 256, 0, stream>>>(psum, y, gamma, beta);
    k_cov    <<<dim3(16, B), 256, 0, stream>>>(y, covf);
    k_lmax   <<<B, 256, 0, stream>>>(covf, cn);
    k_init   <<<(int)(NELEM / 1024), 256, 0, stream>>>(covf, cn, YAh, YAl);

    // Z-free coupled Newton-Schulz: M = Z*Y tracked directly.
    //   R = q(M); Y' = Y*R; M' = R*(M*R).
    // ---- iteration 0 (M0 == Y0):
    k_mgemm<1, 0><<<512, 256, 0, stream>>>(YAh, YAl, YAh, YAl, Rh, Rl,
                                           YAh, YAl, YAh, YAl, Rh, Rl, cn, out);
    k_mgemm<2, 0><<<512, 256, 0, stream>>>(YAh, YAl, Rh, Rl, YBh, YBl,
                                           YAh, YAl, Rh, Rl, YBh, YBl, cn, out);
    k_mgemm<2, 0><<<512, 256, 0, stream>>>(Rh, Rl, YBh, YBl, MBh, MBl,
                                           Rh, Rl, YBh, YBl, MBh, MBl, cn, out);

    u16 *Ych = YBh, *Ycl = YBl, *Yah = YAh, *Yal = YAl;
    u16 *Mch = MBh, *Mcl = MBl, *Mah = MAh, *Mal = MAl;
    for (int itq = 0; itq < NQ_COUPLED; ++itq) {
        // R = q(Mc)
        k_mgemm<1, 0><<<512, 256, 0, stream>>>(Mch, Mcl, Mch, Mcl, Rh, Rl,
                                               Mch, Mcl, Mch, Mcl, Rh, Rl, cn, out);
        // fused: Ya = Yc*R ; U = Mc*R
        k_mgemm<2, 1><<<1024, 256, 0, stream>>>(Ych, Ycl, Rh, Rl, Yah, Yal,
                                                Mch, Mcl, Rh, Rl, Uh, Ul, cn, out);
        // Ma = R*U = R*Mc*R
        k_mgemm<2, 0><<<512, 256, 0, stream>>>(Rh, Rl, Uh, Ul, Mah, Mal,
                                               Rh, Rl, Uh, Ul, Mah, Mal, cn, out);
        u16* t;
        t = Ych; Ych = Yah; Yah = t;  t = Ycl; Ycl = Yal; Yal = t;
        t = Mch; Mch = Mah; Mah = t;  t = Mcl; Mcl = Mal; Mal = t;
    }
    // final: R = q(Mc); out = sqrt(cn) * (Yc*R) upper triangle
    k_mgemm<1, 0><<<512, 256, 0, stream>>>(Mch, Mcl, Mch, Mcl, Rh, Rl,
                                           Mch, Mcl, Mch, Mcl, Rh, Rl, cn, out);
    k_mgemm<3, 0><<<512, 256, 0, stream>>>(Ych, Ycl, Rh, Rl, Uh, Ul,
                                           Ych, Ycl, Rh, Rl, Uh, Ul, cn, out);
}